// Round 6
// baseline (163.719 us; speedup 1.0000x reference)
//
#include <hip/hip_runtime.h>

#define BB 32
#define SS 2048
#define HH 768
#define LL 9
#define NROWS (BB * SS)  // 65536
#define NCHUNK 64
#define TCHUNK 32        // rows per chunk
#define PROBE_MULT 4     // GEMM redundancy for counter visibility

// ---------------------------------------------------------------------------
// stable logsumexp over 9 values
__device__ __forceinline__ float lse9(const float* v) {
  float m = fmaxf(fmaxf(fmaxf(fmaxf(v[0], v[1]), fmaxf(v[2], v[3])),
                        fmaxf(fmaxf(v[4], v[5]), fmaxf(v[6], v[7]))),
                  v[8]);
  float s = 0.f;
#pragma unroll
  for (int k = 0; k < 9; ++k) s += __expf(v[k] - m);
  return m + __logf(s);
}

// ---------------------------------------------------------------------------
// DPP add on the VALU pipe. CTRL is an ICE via template.
template <int CTRL>
__device__ __forceinline__ float dpp_add(float x) {
  int t = __builtin_amdgcn_update_dpp(0, __float_as_int(x), CTRL, 0xf, 0xf, true);
  return x + __int_as_float(t);
}
__device__ __forceinline__ float red16(float x) {
  x = dpp_add<0xB1>(x);   // quad_perm xor1
  x = dpp_add<0x4E>(x);   // quad_perm xor2
  x = dpp_add<0x141>(x);  // row_half_mirror (xor7)
  x = dpp_add<0x140>(x);  // row_mirror (xor15)
  return x;
}

// ---------------------------------------------------------------------------
// PROBE kernel: round-5 phase-A GEMM, grid = PROBE_MULT * 2048.
// Work keyed by (blk & 2047): PROBE_MULT identical passes, identical writes.
// Structure is EXACTLY the round-5 streaming loop so counters explain it.
__global__ __launch_bounds__(256, 4)
void emis_probe(const float* __restrict__ hs, const float* __restrict__ W,
                const float* __restrict__ bias, float* __restrict__ em,
                int* __restrict__ gcnt) {
  const int blk = blockIdx.x & (BB * NCHUNK - 1);
  const int b = blk >> 6, c = blk & 63;
  const int tid = threadIdx.x;
  const int lane = tid & 63;
  const int w = tid >> 6;
  const int half = w & 1;          // k-half
  const int rowg = (w >> 1) * 16;  // row group base
  const int t0 = c * TCHUNK;
  if (blockIdx.x == 0 && tid == 0) *gcnt = 0;  // re-arm fold finalize counter

  __shared__ float part[TCHUNK][8][9];  // 9.2 KB

  const int kb = half * 384;
  float wr[LL][6];
#pragma unroll
  for (int l = 0; l < LL; ++l) {
    float4 t4 = *reinterpret_cast<const float4*>(W + l * HH + kb + lane * 4);
    float2 t2 = *reinterpret_cast<const float2*>(W + l * HH + kb + 256 + lane * 2);
    wr[l][0] = t4.x; wr[l][1] = t4.y; wr[l][2] = t4.z; wr[l][3] = t4.w;
    wr[l][4] = t2.x; wr[l][5] = t2.y;
  }

  const size_t rbase = (size_t)(b * SS + t0 + rowg) * HH + kb;
  const float* r0 = hs + rbase;
  float4 A4 = *reinterpret_cast<const float4*>(r0 + lane * 4);
  float2 A2 = *reinterpret_cast<const float2*>(r0 + 256 + lane * 2);
  const float* r1 = hs + rbase + HH;
  float4 B4 = *reinterpret_cast<const float4*>(r1 + lane * 4);
  float2 B2 = *reinterpret_cast<const float2*>(r1 + 256 + lane * 2);

  const int slot = half * 4 + (lane >> 4);
  const bool wlead = (lane & 15) == 0;

#pragma unroll
  for (int r = 0; r < 16; ++r) {
    float4 cur4 = (r & 1) ? B4 : A4;
    float2 cur2 = (r & 1) ? B2 : A2;
    if (r + 2 < 16) {
      const float* rn = hs + rbase + (size_t)(r + 2) * HH;
      if (r & 1) {
        B4 = *reinterpret_cast<const float4*>(rn + lane * 4);
        B2 = *reinterpret_cast<const float2*>(rn + 256 + lane * 2);
      } else {
        A4 = *reinterpret_cast<const float4*>(rn + lane * 4);
        A2 = *reinterpret_cast<const float2*>(rn + 256 + lane * 2);
      }
    }
    const float h[6] = {cur4.x, cur4.y, cur4.z, cur4.w, cur2.x, cur2.y};
#pragma unroll
    for (int l = 0; l < LL; ++l) {
      float s = h[0] * wr[l][0];
#pragma unroll
      for (int q = 1; q < 6; ++q) s = fmaf(h[q], wr[l][q], s);
      s = red16(s);
      if (wlead) part[rowg + r][slot][l] = s;
    }
  }
  __syncthreads();

  float* emg = em + (size_t)(b * SS + t0) * LL;
  for (int j = tid; j < TCHUNK * LL; j += 256) {
    const int o = j / LL, l = j - o * LL;
    float s = bias[l];
#pragma unroll
    for (int q = 0; q < 8; ++q) s += part[o][q][l];
    emg[j] = s;
  }
}

// ---------------------------------------------------------------------------
// Kernel 2: per-chunk transfer matrix + numerator partial (round-4 form).
__global__ __launch_bounds__(128)
void crf_chunk(const float* __restrict__ em, const int* __restrict__ lab,
               const float* __restrict__ trans, const float* __restrict__ startT,
               float* __restrict__ Pout, float* __restrict__ numpart,
               int* __restrict__ cntpart) {
  const int blk = blockIdx.x;
  const int b = blk >> 6, c = blk & 63;
  const int tid = threadIdx.x;
  const int lane = tid & 63;
  const int wv = tid >> 6;
  __shared__ float em_s[TCHUNK * LL];
  __shared__ int lab_s[TCHUNK + 1];
  __shared__ float Pbuf[2][81];

  const int t0 = c * TCHUNK;
  const size_t ebase = (size_t)(b * SS + t0) * LL;
  for (int i = tid; i < TCHUNK * LL; i += 128) em_s[i] = em[ebase + i];
  if (tid <= TCHUNK) {
    int g = t0 - 1 + tid;
    lab_s[tid] = (g >= 0) ? lab[b * SS + g] : 0;
  }
  const int i9 = tid / 9, j9 = tid % 9;
  float tc[9];
  if (tid < 81) {
#pragma unroll
    for (int k = 0; k < 9; ++k) tc[k] = trans[k * 9 + j9];
  }
  __syncthreads();

  unsigned mask32 =
      (unsigned)__ballot((lane < 32) ? (lab_s[1 + lane] != -100) : false);

  if (wv == 1) {
    float sc = 0.f;
    if (lane < 32) {
      int lv = lab_s[1 + lane];
      int tg = (lv != -100) ? lv : 0;
      if (t0 + lane == 0) {
        sc = startT[tg] + em_s[tg];
      } else if (lv != -100) {
        int pv = lab_s[lane];
        int tp = (pv != -100) ? pv : 0;
        sc = trans[tp * LL + tg] + em_s[lane * LL + tg];
      }
    }
#pragma unroll
    for (int off = 32; off; off >>= 1) sc += __shfl_xor(sc, off, 64);
    if (lane == 0) {
      numpart[blk] = sc;
      cntpart[blk] = __popc(mask32);
    }
  }

  if (tid < 81) Pbuf[0][tid] = (i9 == j9) ? 0.f : -1e30f;
  __syncthreads();
  int cur = 0;
  const int ltstart = (c == 0) ? 1 : 0;  // t=0 is alpha0, not a matrix
  for (int lt = ltstart; lt < TCHUNK; ++lt) {
    if ((mask32 >> lt) & 1u) {
      if (tid < 81) {
        float v[9];
#pragma unroll
        for (int k = 0; k < 9; ++k) v[k] = Pbuf[cur][i9 * 9 + k] + tc[k];
        Pbuf[cur ^ 1][tid] = lse9(v) + em_s[lt * LL + j9];
      }
      __syncthreads();
      cur ^= 1;
    }
  }
  if (tid < 81) Pout[(size_t)blk * 81 + tid] = Pbuf[cur][tid];
}

// ---------------------------------------------------------------------------
// Kernel 3: per-batch tree fold (depth 6) + llh + fused finalize.
__global__ __launch_bounds__(128)
void crf_fold(const float* __restrict__ Pm, const float* __restrict__ em,
              const float* __restrict__ startT, const float* __restrict__ endT,
              const float* __restrict__ numpart, const int* __restrict__ cntpart,
              const int* __restrict__ lab, float* __restrict__ llh,
              int* __restrict__ gcnt, float* __restrict__ out) {
  const int b = blockIdx.x, tid = threadIdx.x;
  __shared__ __align__(16) float Abuf[64 * 81];
  __shared__ __align__(16) float Bbuf[32 * 81];

  const float* src = Pm + (size_t)b * NCHUNK * 81;
  for (int i = tid; i < 64 * 81 / 4; i += 128)
    reinterpret_cast<float4*>(Abuf)[i] = reinterpret_cast<const float4*>(src)[i];
  __syncthreads();

  float* pin = Abuf;
  float* pout = Bbuf;
  for (int n = 32;; n >>= 1) {
    for (int o = tid; o < n * 81; o += 128) {
      int m = o / 81, e = o % 81;
      int i = e / 9, j = e % 9;
      const float* M1 = pin + (2 * m) * 81;
      const float* M2 = pin + (2 * m + 1) * 81;
      float v[9];
#pragma unroll
      for (int k = 0; k < 9; ++k) v[k] = M1[i * 9 + k] + M2[k * 9 + j];
      pout[o] = lse9(v);
    }
    __syncthreads();
    if (n == 1) break;
    float* t = pin; pin = pout;
    pout = (pout == Bbuf) ? Abuf : t;
  }
  const float* fin = pout;

  float ns = 0.f;
  int cn = 0;
  if (tid < 64) {
    ns = numpart[b * 64 + tid];
    cn = cntpart[b * 64 + tid];
#pragma unroll
    for (int off = 32; off; off >>= 1) {
      ns += __shfl_xor(ns, off, 64);
      cn += __shfl_xor(cn, off, 64);
    }
  }
  if (tid == 0) {
    float a0[9], af[9], v[9];
#pragma unroll
    for (int j = 0; j < 9; ++j) a0[j] = startT[j] + em[(size_t)b * SS * LL + j];
#pragma unroll
    for (int j = 0; j < 9; ++j) {
#pragma unroll
      for (int k = 0; k < 9; ++k) v[k] = a0[k] + fin[k * 9 + j];
      af[j] = lse9(v);
    }
#pragma unroll
    for (int j = 0; j < 9; ++j) v[j] = af[j] + endT[j];
    float den = lse9(v);
    int se = cn - 1;
    int lt = lab[b * SS + se];
    if (lt == -100) lt = 0;
    llh[b] = (ns + endT[lt]) - den;

    __threadfence();
    int old = atomicAdd(gcnt, 1);
    if (old == BB - 1) {
      __threadfence();
      float s = 0.f;
      for (int i = 0; i < BB; ++i)
        s += __hip_atomic_load(&llh[i], __ATOMIC_RELAXED,
                               __HIP_MEMORY_SCOPE_AGENT);
      out[0] = -s / (float)BB;
    }
  }
}

// ---------------------------------------------------------------------------
extern "C" void kernel_launch(void* const* d_in, const int* in_sizes, int n_in,
                              void* d_out, int out_size, void* d_ws, size_t ws_size,
                              hipStream_t stream) {
  const float* hs = (const float*)d_in[0];
  const float* W = (const float*)d_in[1];
  const float* bias = (const float*)d_in[2];
  const float* startT = (const float*)d_in[3];
  const float* endT = (const float*)d_in[4];
  const float* trans = (const float*)d_in[5];
  const int* labels = (const int*)d_in[6];

  float* out = (float*)d_out;  // out[0] = loss, out[1..] = emissions [B,S,L]
  float* em = out + 1;

  float* wsf = (float*)d_ws;
  float* llh = wsf;                        // [32]
  int* gcnt = (int*)(wsf + 32);            // [1]
  float* numpart = wsf + 64;               // [B*NCHUNK]
  int* cntpart = (int*)(wsf + 64 + 2048);  // [B*NCHUNK]
  float* Pm = wsf + 64 + 4096;             // [B*NCHUNK*81], 16B-aligned

  emis_probe<<<PROBE_MULT * BB * NCHUNK, 256, 0, stream>>>(hs, W, bias, em, gcnt);
  crf_chunk<<<BB * NCHUNK, 128, 0, stream>>>(em, labels, trans, startT,
                                             Pm, numpart, cntpart);
  crf_fold<<<BB, 128, 0, stream>>>(Pm, em, startT, endT, numpart, cntpart,
                                   labels, llh, gcnt, out);
}

// Round 7
// 77.739 us; speedup vs baseline: 2.1060x; 2.1060x over previous
//
#include <hip/hip_runtime.h>

#define BB 32
#define SS 2048
#define HH 768
#define LL 9
#define NROWS (BB * SS)  // 65536
#define NCHUNK 64
#define TCHUNK 32
#define NSTEP 24             // 768 / 32 k-steps
#define ZSLOT (NSTEP * 36)   // shared all-zero B slot (cols 9..15)

typedef short s16x8 __attribute__((ext_vector_type(8)));
typedef float f32x4 __attribute__((ext_vector_type(4)));

// ---------------------------------------------------------------------------
// stable logsumexp over 9 values
__device__ __forceinline__ float lse9(const float* v) {
  float m = fmaxf(fmaxf(fmaxf(fmaxf(v[0], v[1]), fmaxf(v[2], v[3])),
                        fmaxf(fmaxf(v[4], v[5]), fmaxf(v[6], v[7]))),
                  v[8]);
  float s = 0.f;
#pragma unroll
  for (int k = 0; k < 9; ++k) s += __expf(v[k] - m);
  return m + __logf(s);
}

// ---------------------------------------------------------------------------
__device__ __forceinline__ unsigned cvtpk(float a, float b) {
  unsigned d;  // d.lo = bf16(a), d.hi = bf16(b), RNE
  asm("v_cvt_pk_bf16_f32 %0, %1, %2" : "=v"(d) : "v"(a), "v"(b));
  return d;
}

// split 8 f32 into packed-bf16 hi and lo halves (4 u32 each); x ~= hi + lo
__device__ __forceinline__ void split8(const float* f, unsigned* hi,
                                       unsigned* lo) {
#pragma unroll
  for (int p = 0; p < 4; ++p) {
    unsigned h = cvtpk(f[2 * p], f[2 * p + 1]);
    float h0 = __uint_as_float(h << 16);
    float h1 = __uint_as_float(h & 0xffff0000u);
    lo[p] = cvtpk(f[2 * p] - h0, f[2 * p + 1] - h1);
    hi[p] = h;
  }
}

// ---------------------------------------------------------------------------
// Kernel 1: emissions = hs @ W^T + b via split-bf16 MFMA (fp32-class error).
// Wave = one 16-row tile, 24 K-steps of 32. A frag: row=lane&15,
// k=(lane>>4)*8+j. B frag from LDS (prep once/block): col=lane&15 (<9, else
// shared zero slot), same k. D: col=lane&15, row=(lane>>4)*4+reg (m89 layout).
__global__ __launch_bounds__(256, 3)
void emis_mfma(const float* __restrict__ hs, const float* __restrict__ W,
               const float* __restrict__ bias, float* __restrict__ em,
               int* __restrict__ gcnt) {
  const int tid = threadIdx.x;
  if (blockIdx.x == 0 && tid == 0) *gcnt = 0;  // re-arm fold finalize counter

  __shared__ uint4 Bhi[ZSLOT + 1];  // 13.8 KB
  __shared__ uint4 Blo[ZSLOT + 1];  // 13.8 KB

  // ---- B prep: W -> hi/lo bf16 fragments (9 cols packed + zero slot) ----
  for (int s = tid; s <= ZSLOT; s += 256) {
    float f[8] = {0.f, 0.f, 0.f, 0.f, 0.f, 0.f, 0.f, 0.f};
    if (s < ZSLOT) {
      const int kk = s / 36, rem = s - kk * 36;
      const int kg = rem / 9, col = rem - kg * 9;
      const float* wp = W + col * HH + kk * 32 + kg * 8;
      float4 w0 = *reinterpret_cast<const float4*>(wp);
      float4 w1 = *reinterpret_cast<const float4*>(wp + 4);
      f[0] = w0.x; f[1] = w0.y; f[2] = w0.z; f[3] = w0.w;
      f[4] = w1.x; f[5] = w1.y; f[6] = w1.z; f[7] = w1.w;
    }
    unsigned hi[4], lo[4];
    split8(f, hi, lo);
    Bhi[s] = make_uint4(hi[0], hi[1], hi[2], hi[3]);
    Blo[s] = make_uint4(lo[0], lo[1], lo[2], lo[3]);
  }
  __syncthreads();

  // ---- main: one 16-row tile per wave ----
  const int lane = tid & 63;
  const int w = tid >> 6;
  const int l15 = lane & 15;  // A row / B col / D col
  const int kg = lane >> 4;   // k group
  const int tile = blockIdx.x * 4 + w;

  const float* ab = hs + (size_t)(tile * 16 + l15) * HH + kg * 8;
  const int s0 = (l15 < 9) ? (kg * 9 + l15) : ZSLOT;
  const int sst = (l15 < 9) ? 36 : 0;
  const float bv = (l15 < 9) ? bias[l15] : 0.f;

  f32x4 acc = {0.f, 0.f, 0.f, 0.f};
  float4 pf[3][2];
#pragma unroll
  for (int q = 0; q < 3; ++q) {
    pf[q][0] = *reinterpret_cast<const float4*>(ab + q * 32);
    pf[q][1] = *reinterpret_cast<const float4*>(ab + q * 32 + 4);
  }

#pragma unroll
  for (int kk = 0; kk < NSTEP; ++kk) {
    const float4 u0 = pf[kk % 3][0];
    const float4 u1 = pf[kk % 3][1];
    if (kk + 3 < NSTEP) {  // static under full unroll
      pf[kk % 3][0] = *reinterpret_cast<const float4*>(ab + (kk + 3) * 32);
      pf[kk % 3][1] = *reinterpret_cast<const float4*>(ab + (kk + 3) * 32 + 4);
    }
    float f[8] = {u0.x, u0.y, u0.z, u0.w, u1.x, u1.y, u1.z, u1.w};
    unsigned ah[4], al[4];
    split8(f, ah, al);
    const uint4 bh4 = Bhi[s0 + kk * sst];
    const uint4 bl4 = Blo[s0 + kk * sst];
    const s16x8 Ah = __builtin_bit_cast(s16x8, make_uint4(ah[0], ah[1], ah[2], ah[3]));
    const s16x8 Al = __builtin_bit_cast(s16x8, make_uint4(al[0], al[1], al[2], al[3]));
    const s16x8 Bh = __builtin_bit_cast(s16x8, bh4);
    const s16x8 Bl = __builtin_bit_cast(s16x8, bl4);
    acc = __builtin_amdgcn_mfma_f32_16x16x32_bf16(Ah, Bh, acc, 0, 0, 0);
    acc = __builtin_amdgcn_mfma_f32_16x16x32_bf16(Al, Bh, acc, 0, 0, 0);
    acc = __builtin_amdgcn_mfma_f32_16x16x32_bf16(Ah, Bl, acc, 0, 0, 0);
  }

  if (l15 < 9) {  // D: row = kg*4 + reg, col = l15
    float* o = em + (size_t)(tile * 16 + kg * 4) * LL + l15;
    o[0] = acc[0] + bv;
    o[LL] = acc[1] + bv;
    o[2 * LL] = acc[2] + bv;
    o[3 * LL] = acc[3] + bv;
  }
}

// ---------------------------------------------------------------------------
// Kernel 2: per-chunk transfer matrix + numerator partial (proven form).
__global__ __launch_bounds__(128)
void crf_chunk(const float* __restrict__ em, const int* __restrict__ lab,
               const float* __restrict__ trans, const float* __restrict__ startT,
               float* __restrict__ Pout, float* __restrict__ numpart,
               int* __restrict__ cntpart) {
  const int blk = blockIdx.x;
  const int b = blk >> 6, c = blk & 63;
  const int tid = threadIdx.x;
  const int lane = tid & 63;
  const int wv = tid >> 6;
  __shared__ float em_s[TCHUNK * LL];
  __shared__ int lab_s[TCHUNK + 1];
  __shared__ float Pbuf[2][81];

  const int t0 = c * TCHUNK;
  const size_t ebase = (size_t)(b * SS + t0) * LL;
  for (int i = tid; i < TCHUNK * LL; i += 128) em_s[i] = em[ebase + i];
  if (tid <= TCHUNK) {
    int g = t0 - 1 + tid;
    lab_s[tid] = (g >= 0) ? lab[b * SS + g] : 0;
  }
  const int i9 = tid / 9, j9 = tid % 9;
  float tc[9];
  if (tid < 81) {
#pragma unroll
    for (int k = 0; k < 9; ++k) tc[k] = trans[k * 9 + j9];
  }
  __syncthreads();

  unsigned mask32 =
      (unsigned)__ballot((lane < 32) ? (lab_s[1 + lane] != -100) : false);

  if (wv == 1) {
    float sc = 0.f;
    if (lane < 32) {
      int lv = lab_s[1 + lane];
      int tg = (lv != -100) ? lv : 0;
      if (t0 + lane == 0) {
        sc = startT[tg] + em_s[tg];
      } else if (lv != -100) {
        int pv = lab_s[lane];
        int tp = (pv != -100) ? pv : 0;
        sc = trans[tp * LL + tg] + em_s[lane * LL + tg];
      }
    }
#pragma unroll
    for (int off = 32; off; off >>= 1) sc += __shfl_xor(sc, off, 64);
    if (lane == 0) {
      numpart[blk] = sc;
      cntpart[blk] = __popc(mask32);
    }
  }

  if (tid < 81) Pbuf[0][tid] = (i9 == j9) ? 0.f : -1e30f;
  __syncthreads();
  int cur = 0;
  const int ltstart = (c == 0) ? 1 : 0;  // t=0 is alpha0, not a matrix
  for (int lt = ltstart; lt < TCHUNK; ++lt) {
    if ((mask32 >> lt) & 1u) {
      if (tid < 81) {
        float v[9];
#pragma unroll
        for (int k = 0; k < 9; ++k) v[k] = Pbuf[cur][i9 * 9 + k] + tc[k];
        Pbuf[cur ^ 1][tid] = lse9(v) + em_s[lt * LL + j9];
      }
      __syncthreads();
      cur ^= 1;
    }
  }
  if (tid < 81) Pout[(size_t)blk * 81 + tid] = Pbuf[cur][tid];
}

// ---------------------------------------------------------------------------
// Kernel 3: per-batch tree fold (depth 6) + llh + fused finalize.
__global__ __launch_bounds__(128)
void crf_fold(const float* __restrict__ Pm, const float* __restrict__ em,
              const float* __restrict__ startT, const float* __restrict__ endT,
              const float* __restrict__ numpart, const int* __restrict__ cntpart,
              const int* __restrict__ lab, float* __restrict__ llh,
              int* __restrict__ gcnt, float* __restrict__ out) {
  const int b = blockIdx.x, tid = threadIdx.x;
  __shared__ __align__(16) float Abuf[64 * 81];
  __shared__ __align__(16) float Bbuf[32 * 81];

  const float* src = Pm + (size_t)b * NCHUNK * 81;
  for (int i = tid; i < 64 * 81 / 4; i += 128)
    reinterpret_cast<float4*>(Abuf)[i] = reinterpret_cast<const float4*>(src)[i];
  __syncthreads();

  float* pin = Abuf;
  float* pout = Bbuf;
  for (int n = 32;; n >>= 1) {
    for (int o = tid; o < n * 81; o += 128) {
      int m = o / 81, e = o % 81;
      int i = e / 9, j = e % 9;
      const float* M1 = pin + (2 * m) * 81;
      const float* M2 = pin + (2 * m + 1) * 81;
      float v[9];
#pragma unroll
      for (int k = 0; k < 9; ++k) v[k] = M1[i * 9 + k] + M2[k * 9 + j];
      pout[o] = lse9(v);
    }
    __syncthreads();
    if (n == 1) break;
    float* t = pin; pin = pout;
    pout = (pout == Bbuf) ? Abuf : t;
  }
  const float* fin = pout;

  float ns = 0.f;
  int cn = 0;
  if (tid < 64) {
    ns = numpart[b * 64 + tid];
    cn = cntpart[b * 64 + tid];
#pragma unroll
    for (int off = 32; off; off >>= 1) {
      ns += __shfl_xor(ns, off, 64);
      cn += __shfl_xor(cn, off, 64);
    }
  }
  if (tid == 0) {
    float a0[9], af[9], v[9];
#pragma unroll
    for (int j = 0; j < 9; ++j) a0[j] = startT[j] + em[(size_t)b * SS * LL + j];
#pragma unroll
    for (int j = 0; j < 9; ++j) {
#pragma unroll
      for (int k = 0; k < 9; ++k) v[k] = a0[k] + fin[k * 9 + j];
      af[j] = lse9(v);
    }
#pragma unroll
    for (int j = 0; j < 9; ++j) v[j] = af[j] + endT[j];
    float den = lse9(v);
    int se = cn - 1;
    int lt = lab[b * SS + se];
    if (lt == -100) lt = 0;
    llh[b] = (ns + endT[lt]) - den;

    __threadfence();
    int old = atomicAdd(gcnt, 1);
    if (old == BB - 1) {  // last block finalizes in fixed order
      __threadfence();
      float s = 0.f;
      for (int i = 0; i < BB; ++i)
        s += __hip_atomic_load(&llh[i], __ATOMIC_RELAXED,
                               __HIP_MEMORY_SCOPE_AGENT);
      out[0] = -s / (float)BB;
    }
  }
}

// ---------------------------------------------------------------------------
extern "C" void kernel_launch(void* const* d_in, const int* in_sizes, int n_in,
                              void* d_out, int out_size, void* d_ws, size_t ws_size,
                              hipStream_t stream) {
  const float* hs = (const float*)d_in[0];
  const float* W = (const float*)d_in[1];
  const float* bias = (const float*)d_in[2];
  const float* startT = (const float*)d_in[3];
  const float* endT = (const float*)d_in[4];
  const float* trans = (const float*)d_in[5];
  const int* labels = (const int*)d_in[6];

  float* out = (float*)d_out;  // out[0] = loss, out[1..] = emissions [B,S,L]
  float* em = out + 1;

  float* wsf = (float*)d_ws;
  float* llh = wsf;                        // [32]
  int* gcnt = (int*)(wsf + 32);            // [1]
  float* numpart = wsf + 64;               // [B*NCHUNK]
  int* cntpart = (int*)(wsf + 64 + 2048);  // [B*NCHUNK]
  float* Pm = wsf + 64 + 4096;             // [B*NCHUNK*81], 16B-aligned

  emis_mfma<<<NROWS / 64, 256, 0, stream>>>(hs, W, bias, em, gcnt);
  crf_chunk<<<BB * NCHUNK, 128, 0, stream>>>(em, labels, trans, startT,
                                             Pm, numpart, cntpart);
  crf_fold<<<BB, 128, 0, stream>>>(Pm, em, startT, endT, numpart, cntpart,
                                   labels, llh, gcnt, out);
}